// Round 1
// 82.219 us; speedup vs baseline: 1.1154x; 1.1154x over previous
//
#include <hip/hip_runtime.h>
#include <math.h>

// Problem constants
#define B 2
#define N 8192            // points per batch
#define PTS_STRIDE (N*3)
#define VOXEL 0.1f

#define CBLK 128          // chamfer: 2 waves per block, no LDS, no barriers
#define XPB 64            // x-points per chamfer block (4 fused B-frags per wave)

// ws layout (float offsets); ws_size >= 17 MB known, we use ~2.7 MB.
//  [16] acc   [17] ticket
//  WS_MINS: uint mins[slot(4)][var(2)][x(8192)]  (monotone-encoded float, init 0xFF800000)
//  OFF_PACK per g=arr*2+b (PERG=147456 floats):
//    AFLO[N] short8: [y0,y1,y2,yyh,yyl,w0,w1,w2]   (A rows, k=0..7)
//    AFHI[N] short8: [vvh,vvl,0,...]               (A rows, k=8..15)
//    BR[N]   short8: [-2x0,-2x1,-2x2,1,1,0,0,0]    (B raw col, k=0..7)
//    BV[N]   short8: [0,0,0,0,0,-2u0,-2u1,-2u2]    (B vox col, k=0..7)
//    XXR[N], XXV[N] f32
//  WS_PART: gmin partials, 64 blocks x 3 floats
#define WS_ACC 16
#define WS_TICKET 17
#define WS_MINS 32
#define MINS_TOTAL 65536
#define OFF_PACK (WS_MINS + MINS_TOTAL)
#define PERG 147456
#define OFF_AFLO(g) (OFF_PACK + (g)*PERG)
#define OFF_AFHI(g) (OFF_AFLO(g) + 32768)
#define OFF_BR(g)   (OFF_AFLO(g) + 65536)
#define OFF_BV(g)   (OFF_AFLO(g) + 98304)
#define OFF_XXR(g)  (OFF_AFLO(g) + 131072)
#define OFF_XXV(g)  (OFF_AFLO(g) + 139264)
#define WS_PART (OFF_PACK + 4*PERG)

typedef __attribute__((ext_vector_type(8))) short short8;    // 8 bf16 (MFMA A/B frag)
typedef __attribute__((ext_vector_type(16))) float f16v;     // 32x32 MFMA C/D frag

union S8 { short8 v; unsigned short u[8]; };

__device__ __forceinline__ unsigned short f2bf(float f) {    // RNE f32->bf16
    unsigned u = __float_as_uint(f);
    return (unsigned short)((u + 0x7FFFu + ((u >> 16) & 1u)) >> 16);
}
__device__ __forceinline__ float bf2f(unsigned short h) {
    return __uint_as_float(((unsigned)h) << 16);
}
__device__ __forceinline__ float voxq(float v, float g) {
    return (float)(int)((v - g) / VOXEL);   // trunc like .astype(int32)
}
// monotone float->uint (unsigned order == float order, handles negatives)
__device__ __forceinline__ unsigned fenc(float f) {
    const unsigned u = __float_as_uint(f);
    return (u & 0x80000000u) ? ~u : (u | 0x80000000u);
}
__device__ __forceinline__ float fdec(unsigned k) {
    const unsigned u = (k & 0x80000000u) ? (k & 0x7FFFFFFFu) : ~k;
    return __uint_as_float(u);
}
// nested fminf triple -> v_min3_f32
__device__ __forceinline__ float min3f(float a, float b, float c) {
    return fminf(fminf(a, b), c);
}
// fold 16-reg MFMA tile into running min: 5+2+1 = 8 min3-class ops
__device__ __forceinline__ void fold16(const f16v d, float& mn) {
    const float t0 = min3f(d[0],  d[1],  d[2]);
    const float t1 = min3f(d[3],  d[4],  d[5]);
    const float t2 = min3f(d[6],  d[7],  d[8]);
    const float t3 = min3f(d[9],  d[10], d[11]);
    const float t4 = min3f(d[12], d[13], d[14]);
    const float u0 = min3f(t0, t1, t2);
    const float u1 = min3f(t3, t4, d[15]);
    mn = min3f(mn, u0, u1);
}

// 64 blocks (16 per g) x 256 threads: per-block partial min -> WS_PART.
__global__ void __launch_bounds__(256)
gmin_kernel(const float* __restrict__ preds,
            const float* __restrict__ gts,
            float* __restrict__ ws) {
    const int blk = blockIdx.x;        // 0..63
    const int g   = blk >> 4;          // g = arr*2 + b
    const int sub = blk & 15;
    const int arr = g >> 1;
    const int b   = g & 1;
    const float* base = (arr ? gts : preds) + b * PTS_STRIDE;

    float m0 = INFINITY, m1 = INFINITY, m2 = INFINITY;
#pragma unroll
    for (int j = 0; j < 2; ++j) {
        const int idx = (sub << 9) + (j << 8) + threadIdx.x;   // 512 pts/block
        float v;
        v = base[idx*3+0]; m0 = fminf(m0, (v!=v)?INFINITY:v);
        v = base[idx*3+1]; m1 = fminf(m1, (v!=v)?INFINITY:v);
        v = base[idx*3+2]; m2 = fminf(m2, (v!=v)?INFINITY:v);
    }
    for (int off = 32; off; off >>= 1) {
        m0 = fminf(m0, __shfl_down(m0, off));
        m1 = fminf(m1, __shfl_down(m1, off));
        m2 = fminf(m2, __shfl_down(m2, off));
    }
    __shared__ float sm[4][3];
    const int wave = threadIdx.x >> 6, lane = threadIdx.x & 63;
    if (lane == 0) { sm[wave][0] = m0; sm[wave][1] = m1; sm[wave][2] = m2; }
    __syncthreads();
    if (threadIdx.x == 0) {
        const float a0 = fminf(fminf(sm[0][0], sm[1][0]), fminf(sm[2][0], sm[3][0]));
        const float a1 = fminf(fminf(sm[0][1], sm[1][1]), fminf(sm[2][1], sm[3][1]));
        const float a2 = fminf(fminf(sm[0][2], sm[1][2]), fminf(sm[2][2], sm[3][2]));
        ws[WS_PART + blk*3+0] = a0;
        ws[WS_PART + blk*3+1] = a1;
        ws[WS_PART + blk*3+2] = a2;
        if (blk == 0) { ws[WS_ACC] = 0.0f; ((unsigned*)ws)[WS_TICKET] = 0u; }
    }
}

// One thread per point (128 blocks x 256 = 32768): reduce gmin partials,
// build fragments + init mins.
__global__ void __launch_bounds__(256)
pack_kernel(const float* __restrict__ preds,
            const float* __restrict__ gts,
            float* __restrict__ ws) {
    const int i   = blockIdx.x * 256 + threadIdx.x;   // 0..32767
    const int g   = i >> 13;                          // uniform per block
    const int idx = i & (N-1);
    const int arr = g >> 1;
    const int b   = g & 1;
    const float* base = (arr ? gts : preds) + b * PTS_STRIDE;

    // init encoded-min array (2 entries per thread): enc(+inf) = 0xFF800000
    unsigned* mins = (unsigned*)ws + WS_MINS;
    mins[i] = 0xFF800000u;
    mins[i + 32768] = 0xFF800000u;

    // reduce this g's 16 partial mins (uniform addresses -> broadcast loads)
    float g0 = INFINITY, g1 = INFINITY, g2 = INFINITY;
#pragma unroll
    for (int w = 0; w < 16; ++w) {
        g0 = fminf(g0, ws[WS_PART + (g*16 + w)*3 + 0]);
        g1 = fminf(g1, ws[WS_PART + (g*16 + w)*3 + 1]);
        g2 = fminf(g2, ws[WS_PART + (g*16 + w)*3 + 2]);
    }

    const float p0 = base[idx*3+0], p1 = base[idx*3+1], p2 = base[idx*3+2];
    const float w0 = voxq(p0, g0), w1 = voxq(p1, g1), w2 = voxq(p2, g2);
    const float rr = fmaf(p0,p0, fmaf(p1,p1, p2*p2));
    const float vv = fmaf(w0,w0, fmaf(w1,w1, w2*w2));

    const unsigned short yyh = f2bf(rr);
    const unsigned short yyl = f2bf(rr - bf2f(yyh));
    const unsigned short vvh = f2bf(vv);
    const unsigned short vvl = f2bf(vv - bf2f(vvh));
    const unsigned short ONE = 0x3F80;

    short8* AFLO = (short8*)(ws + OFF_AFLO(g));
    short8* AFHI = (short8*)(ws + OFF_AFHI(g));
    short8* BR   = (short8*)(ws + OFF_BR(g));
    short8* BV   = (short8*)(ws + OFF_BV(g));

    S8 f;
    // A lo (k=0..7): [y0,y1,y2,yyh,yyl, w0,w1,w2]
    f.u[0]=f2bf(p0); f.u[1]=f2bf(p1); f.u[2]=f2bf(p2);
    f.u[3]=yyh; f.u[4]=yyl; f.u[5]=f2bf(w0); f.u[6]=f2bf(w1); f.u[7]=f2bf(w2);
    AFLO[idx] = f.v;
    // A hi (k=8..15): [vvh,vvl,0...]
    f.u[0]=vvh; f.u[1]=vvl; f.u[2]=0; f.u[3]=0; f.u[4]=0; f.u[5]=0; f.u[6]=0; f.u[7]=0;
    AFHI[idx] = f.v;
    // B raw col (k=0..7)
    f.u[0]=f2bf(-2.0f*p0); f.u[1]=f2bf(-2.0f*p1); f.u[2]=f2bf(-2.0f*p2);
    f.u[3]=ONE; f.u[4]=ONE; f.u[5]=0; f.u[6]=0; f.u[7]=0;
    BR[idx] = f.v;
    // B vox col (k=0..7)
    f.u[0]=0; f.u[1]=0; f.u[2]=0; f.u[3]=0; f.u[4]=0;
    f.u[5]=f2bf(-2.0f*w0); f.u[6]=f2bf(-2.0f*w1); f.u[7]=f2bf(-2.0f*w2);
    BV[idx] = f.v;
    ws[OFF_XXR(g) + idx] = rr;
    ws[OFF_XXV(g) + idx] = vv;
}

// Chamfer: 2048 blocks (128 xtiles x 4 ysplits x 4 slots) x 128 threads.
// 2 independent waves per block; wave w covers y in [(ysplit*2+w)*1024, +1024).
// Per wave: 4 fused B-frags (64 x-points; cols n<16 raw x_n, n>=16 vox x_{n-16})
// so each 16B A-load feeds 4 MFMAs (A-read L2 traffic halved vs 2-frag).
// A-frags straight from global (coalesced 16B/lane). No LDS, no __syncthreads.
// Combine: monotone-encoded atomicMin per (slot,var,x); |x|^2 added in finalize.
__global__ void __launch_bounds__(CBLK, 4)
chamfer_kernel(float* __restrict__ ws) {
    const int tid  = threadIdx.x;
    const int wave = tid >> 6, lane = tid & 63;
    const int half = lane >> 5, c32 = lane & 31;
    const int slot = blockIdx.z;           // 0..3
    const int dir  = slot & 1;
    const int b    = slot >> 1;
    const int gX = dir*2 + b;
    const int gY = (1-dir)*2 + b;

    const short8* Abase = (const short8*)(ws + (half ? OFF_AFHI(gY) : OFF_AFLO(gY)));
    const short8* BR = (const short8*)(ws + OFF_BR(gX));
    const short8* BV = (const short8*)(ws + OFF_BV(gX));

    // 4 fused B-frags for this block's 64 x
    const int xbase = blockIdx.x * XPB;
    S8 hc;
    hc.u[0] = (c32 < 16) ? (unsigned short)0 : (unsigned short)0x3F80;
    hc.u[1] = hc.u[0];
    hc.u[2]=0; hc.u[3]=0; hc.u[4]=0; hc.u[5]=0; hc.u[6]=0; hc.u[7]=0;
    const int xcol0 = xbase + (c32 & 15);
    const short8* Bsel = (c32 < 16) ? BR : BV;
    const short8 bf0 = (half == 0) ? Bsel[xcol0]      : hc.v;
    const short8 bf1 = (half == 0) ? Bsel[xcol0 + 16] : hc.v;
    const short8 bf2 = (half == 0) ? Bsel[xcol0 + 32] : hc.v;
    const short8 bf3 = (half == 0) ? Bsel[xcol0 + 48] : hc.v;

    float mn0 = INFINITY, mn1 = INFINITY, mn2 = INFINITY, mn3 = INFINITY;
    const f16v Z = (f16v)(0.0f);
    const int abase0 = (blockIdx.y * 2 + wave) * 1024 + c32;

#pragma unroll 2
    for (int t = 0; t < 32; ++t) {         // 32 y-tiles of 32
        const short8 a = Abase[abase0 + t*32];
        f16v d;
        d = __builtin_amdgcn_mfma_f32_32x32x16_bf16(a, bf0, Z, 0, 0, 0);
        fold16(d, mn0);
        d = __builtin_amdgcn_mfma_f32_32x32x16_bf16(a, bf1, Z, 0, 0, 0);
        fold16(d, mn1);
        d = __builtin_amdgcn_mfma_f32_32x32x16_bf16(a, bf2, Z, 0, 0, 0);
        fold16(d, mn2);
        d = __builtin_amdgcn_mfma_f32_32x32x16_bf16(a, bf3, Z, 0, 0, 0);
        fold16(d, mn3);
    }

    // other 16 rows live in the xor-32 partner lane (same column)
    mn0 = fminf(mn0, __shfl_xor(mn0, 32));
    mn1 = fminf(mn1, __shfl_xor(mn1, 32));
    mn2 = fminf(mn2, __shfl_xor(mn2, 32));
    mn3 = fminf(mn3, __shfl_xor(mn3, 32));

    if (half == 0) {
        unsigned* mins = (unsigned*)ws + WS_MINS;
        const int var = (c32 < 16) ? 0 : 1;
        const int e0 = ((slot*2 + var) << 13) + xcol0;
        atomicMin(&mins[e0],      fenc(mn0));
        atomicMin(&mins[e0 + 16], fenc(mn1));
        atomicMin(&mins[e0 + 32], fenc(mn2));
        atomicMin(&mins[e0 + 48], fenc(mn3));
    }
}

// 128 blocks x 256: one thread per (slot,x). Decode, add |x|^2, sum, ticket-out.
__global__ void __launch_bounds__(256)
finalize_kernel(float* __restrict__ ws, float* __restrict__ out) {
    const int g = blockIdx.x * 256 + threadIdx.x;   // 0..32767
    const int slot = g >> 13;
    const int x    = g & (N-1);
    const int dir  = slot & 1;
    const int b    = slot >> 1;
    const int gX   = dir*2 + b;
    const unsigned* mins = (const unsigned*)ws + WS_MINS;
    float s = fdec(mins[((slot*2 + 0) << 13) + x]) + ws[OFF_XXR(gX) + x]
            + fdec(mins[((slot*2 + 1) << 13) + x]) + ws[OFF_XXV(gX) + x];
    for (int off = 32; off; off >>= 1)
        s += __shfl_down(s, off);
    __shared__ float sm[4];
    const int wave = threadIdx.x >> 6, lane = threadIdx.x & 63;
    if (lane == 0) sm[wave] = s;
    __syncthreads();
    if (threadIdx.x == 0) {
        const float bs = sm[0] + sm[1] + sm[2] + sm[3];
        atomicAdd(ws + WS_ACC, bs);
        __threadfence();
        const unsigned t = atomicAdd(&((unsigned*)ws)[WS_TICKET], 1u);
        if (t == gridDim.x - 1) {
            __threadfence();
            const float total = atomicAdd(ws + WS_ACC, 0.0f);  // atomic read
            out[0] = total * (1.0f / 16384.0f);
        }
    }
}

extern "C" void kernel_launch(void* const* d_in, const int* in_sizes, int n_in,
                              void* d_out, int out_size, void* d_ws, size_t ws_size,
                              hipStream_t stream) {
    const float* preds = (const float*)d_in[0];
    const float* gts   = (const float*)d_in[1];
    float* ws  = (float*)d_ws;
    float* out = (float*)d_out;

    gmin_kernel<<<dim3(64), dim3(256), 0, stream>>>(preds, gts, ws);
    pack_kernel<<<dim3(128), dim3(256), 0, stream>>>(preds, gts, ws);
    chamfer_kernel<<<dim3(N/XPB, 4, 4), dim3(CBLK), 0, stream>>>(ws);
    finalize_kernel<<<dim3(128), dim3(256), 0, stream>>>(ws, out);
}

// Round 2
// 82.166 us; speedup vs baseline: 1.1161x; 1.0006x over previous
//
#include <hip/hip_runtime.h>
#include <math.h>

// Problem constants
#define B 2
#define N 8192            // points per batch
#define PTS_STRIDE (N*3)
#define VOXEL 0.1f

#define CBLK 128          // chamfer: 2 waves per block, no LDS, no barriers
#define XPB 128           // x-points per chamfer block (8 fused B-frags per wave)

// ws layout (float offsets); ws_size >= 17 MB known, we use ~2.7 MB.
//  [16] acc   [17] ticket
//  WS_MINS: uint mins[slot(4)][var(2)][x(8192)]  (monotone-encoded float, init 0xFF800000)
//  OFF_PACK per g=arr*2+b (PERG=147456 floats):
//    AFLO[N] short8: [y0,y1,y2,yyh,yyl,w0,w1,w2]   (A rows, k=0..7)
//    AFHI[N] short8: [vvh,vvl,0,...]               (A rows, k=8..15)
//    BR[N]   short8: [-2x0,-2x1,-2x2,1,1,0,0,0]    (B raw col, k=0..7)
//    BV[N]   short8: [0,0,0,0,0,-2u0,-2u1,-2u2]    (B vox col, k=0..7)
//    XXR[N], XXV[N] f32
//  WS_PART: gmin partials, 64 blocks x 3 floats
#define WS_ACC 16
#define WS_TICKET 17
#define WS_MINS 32
#define MINS_TOTAL 65536
#define OFF_PACK (WS_MINS + MINS_TOTAL)
#define PERG 147456
#define OFF_AFLO(g) (OFF_PACK + (g)*PERG)
#define OFF_AFHI(g) (OFF_AFLO(g) + 32768)
#define OFF_BR(g)   (OFF_AFLO(g) + 65536)
#define OFF_BV(g)   (OFF_AFLO(g) + 98304)
#define OFF_XXR(g)  (OFF_AFLO(g) + 131072)
#define OFF_XXV(g)  (OFF_AFLO(g) + 139264)
#define WS_PART (OFF_PACK + 4*PERG)

typedef __attribute__((ext_vector_type(8))) short short8;    // 8 bf16 (MFMA A/B frag)
typedef __attribute__((ext_vector_type(16))) float f16v;     // 32x32 MFMA C/D frag

union S8 { short8 v; unsigned short u[8]; };

__device__ __forceinline__ unsigned short f2bf(float f) {    // RNE f32->bf16
    unsigned u = __float_as_uint(f);
    return (unsigned short)((u + 0x7FFFu + ((u >> 16) & 1u)) >> 16);
}
__device__ __forceinline__ float bf2f(unsigned short h) {
    return __uint_as_float(((unsigned)h) << 16);
}
__device__ __forceinline__ float voxq(float v, float g) {
    return (float)(int)((v - g) / VOXEL);   // trunc like .astype(int32)
}
// monotone float->uint (unsigned order == float order, handles negatives)
__device__ __forceinline__ unsigned fenc(float f) {
    const unsigned u = __float_as_uint(f);
    return (u & 0x80000000u) ? ~u : (u | 0x80000000u);
}
__device__ __forceinline__ float fdec(unsigned k) {
    const unsigned u = (k & 0x80000000u) ? (k & 0x7FFFFFFFu) : ~k;
    return __uint_as_float(u);
}
// nested fminf triple -> v_min3_f32
__device__ __forceinline__ float min3f(float a, float b, float c) {
    return fminf(fminf(a, b), c);
}
// fold 16-reg MFMA tile into running min: 5+2+1 = 8 min3-class ops
__device__ __forceinline__ void fold16(const f16v d, float& mn) {
    const float t0 = min3f(d[0],  d[1],  d[2]);
    const float t1 = min3f(d[3],  d[4],  d[5]);
    const float t2 = min3f(d[6],  d[7],  d[8]);
    const float t3 = min3f(d[9],  d[10], d[11]);
    const float t4 = min3f(d[12], d[13], d[14]);
    const float u0 = min3f(t0, t1, t2);
    const float u1 = min3f(t3, t4, d[15]);
    mn = min3f(mn, u0, u1);
}

// 64 blocks (16 per g) x 256 threads: per-block partial min -> WS_PART.
__global__ void __launch_bounds__(256)
gmin_kernel(const float* __restrict__ preds,
            const float* __restrict__ gts,
            float* __restrict__ ws) {
    const int blk = blockIdx.x;        // 0..63
    const int g   = blk >> 4;          // g = arr*2 + b
    const int sub = blk & 15;
    const int arr = g >> 1;
    const int b   = g & 1;
    const float* base = (arr ? gts : preds) + b * PTS_STRIDE;

    float m0 = INFINITY, m1 = INFINITY, m2 = INFINITY;
#pragma unroll
    for (int j = 0; j < 2; ++j) {
        const int idx = (sub << 9) + (j << 8) + threadIdx.x;   // 512 pts/block
        float v;
        v = base[idx*3+0]; m0 = fminf(m0, (v!=v)?INFINITY:v);
        v = base[idx*3+1]; m1 = fminf(m1, (v!=v)?INFINITY:v);
        v = base[idx*3+2]; m2 = fminf(m2, (v!=v)?INFINITY:v);
    }
    for (int off = 32; off; off >>= 1) {
        m0 = fminf(m0, __shfl_down(m0, off));
        m1 = fminf(m1, __shfl_down(m1, off));
        m2 = fminf(m2, __shfl_down(m2, off));
    }
    __shared__ float sm[4][3];
    const int wave = threadIdx.x >> 6, lane = threadIdx.x & 63;
    if (lane == 0) { sm[wave][0] = m0; sm[wave][1] = m1; sm[wave][2] = m2; }
    __syncthreads();
    if (threadIdx.x == 0) {
        const float a0 = fminf(fminf(sm[0][0], sm[1][0]), fminf(sm[2][0], sm[3][0]));
        const float a1 = fminf(fminf(sm[0][1], sm[1][1]), fminf(sm[2][1], sm[3][1]));
        const float a2 = fminf(fminf(sm[0][2], sm[1][2]), fminf(sm[2][2], sm[3][2]));
        ws[WS_PART + blk*3+0] = a0;
        ws[WS_PART + blk*3+1] = a1;
        ws[WS_PART + blk*3+2] = a2;
        if (blk == 0) { ws[WS_ACC] = 0.0f; ((unsigned*)ws)[WS_TICKET] = 0u; }
    }
}

// One thread per point (128 blocks x 256 = 32768): reduce gmin partials,
// build fragments + init mins.
__global__ void __launch_bounds__(256)
pack_kernel(const float* __restrict__ preds,
            const float* __restrict__ gts,
            float* __restrict__ ws) {
    const int i   = blockIdx.x * 256 + threadIdx.x;   // 0..32767
    const int g   = i >> 13;                          // uniform per block
    const int idx = i & (N-1);
    const int arr = g >> 1;
    const int b   = g & 1;
    const float* base = (arr ? gts : preds) + b * PTS_STRIDE;

    // init encoded-min array (2 entries per thread): enc(+inf) = 0xFF800000
    unsigned* mins = (unsigned*)ws + WS_MINS;
    mins[i] = 0xFF800000u;
    mins[i + 32768] = 0xFF800000u;

    // reduce this g's 16 partial mins (uniform addresses -> broadcast loads)
    float g0 = INFINITY, g1 = INFINITY, g2 = INFINITY;
#pragma unroll
    for (int w = 0; w < 16; ++w) {
        g0 = fminf(g0, ws[WS_PART + (g*16 + w)*3 + 0]);
        g1 = fminf(g1, ws[WS_PART + (g*16 + w)*3 + 1]);
        g2 = fminf(g2, ws[WS_PART + (g*16 + w)*3 + 2]);
    }

    const float p0 = base[idx*3+0], p1 = base[idx*3+1], p2 = base[idx*3+2];
    const float w0 = voxq(p0, g0), w1 = voxq(p1, g1), w2 = voxq(p2, g2);
    const float rr = fmaf(p0,p0, fmaf(p1,p1, p2*p2));
    const float vv = fmaf(w0,w0, fmaf(w1,w1, w2*w2));

    const unsigned short yyh = f2bf(rr);
    const unsigned short yyl = f2bf(rr - bf2f(yyh));
    const unsigned short vvh = f2bf(vv);
    const unsigned short vvl = f2bf(vv - bf2f(vvh));
    const unsigned short ONE = 0x3F80;

    short8* AFLO = (short8*)(ws + OFF_AFLO(g));
    short8* AFHI = (short8*)(ws + OFF_AFHI(g));
    short8* BR   = (short8*)(ws + OFF_BR(g));
    short8* BV   = (short8*)(ws + OFF_BV(g));

    S8 f;
    // A lo (k=0..7): [y0,y1,y2,yyh,yyl, w0,w1,w2]
    f.u[0]=f2bf(p0); f.u[1]=f2bf(p1); f.u[2]=f2bf(p2);
    f.u[3]=yyh; f.u[4]=yyl; f.u[5]=f2bf(w0); f.u[6]=f2bf(w1); f.u[7]=f2bf(w2);
    AFLO[idx] = f.v;
    // A hi (k=8..15): [vvh,vvl,0...]
    f.u[0]=vvh; f.u[1]=vvl; f.u[2]=0; f.u[3]=0; f.u[4]=0; f.u[5]=0; f.u[6]=0; f.u[7]=0;
    AFHI[idx] = f.v;
    // B raw col (k=0..7)
    f.u[0]=f2bf(-2.0f*p0); f.u[1]=f2bf(-2.0f*p1); f.u[2]=f2bf(-2.0f*p2);
    f.u[3]=ONE; f.u[4]=ONE; f.u[5]=0; f.u[6]=0; f.u[7]=0;
    BR[idx] = f.v;
    // B vox col (k=0..7)
    f.u[0]=0; f.u[1]=0; f.u[2]=0; f.u[3]=0; f.u[4]=0;
    f.u[5]=f2bf(-2.0f*w0); f.u[6]=f2bf(-2.0f*w1); f.u[7]=f2bf(-2.0f*w2);
    BV[idx] = f.v;
    ws[OFF_XXR(g) + idx] = rr;
    ws[OFF_XXV(g) + idx] = vv;
}

// Chamfer: 2048 blocks (64 xtiles x 8 ysplits x 4 slots) x 128 threads.
// 2 independent waves per block; wave w covers y in [(ysplit*2+w)*512, +512).
// Per wave: 8 fused B-frags (128 x-points; cols n<16 raw x_n, n>=16 vox x_{n-16})
// so each 16B A-load feeds 8 MFMAs (A-read L2 traffic halved again vs 4-frag).
// A-frags straight from global (coalesced 16B/lane). No LDS, no __syncthreads.
// Combine: monotone-encoded atomicMin per (slot,var,x); |x|^2 added in finalize.
__global__ void __launch_bounds__(CBLK, 4)
chamfer_kernel(float* __restrict__ ws) {
    const int tid  = threadIdx.x;
    const int wave = tid >> 6, lane = tid & 63;
    const int half = lane >> 5, c32 = lane & 31;
    const int slot = blockIdx.z;           // 0..3
    const int dir  = slot & 1;
    const int b    = slot >> 1;
    const int gX = dir*2 + b;
    const int gY = (1-dir)*2 + b;

    const short8* Abase = (const short8*)(ws + (half ? OFF_AFHI(gY) : OFF_AFLO(gY)));
    const short8* BR = (const short8*)(ws + OFF_BR(gX));
    const short8* BV = (const short8*)(ws + OFF_BV(gX));

    // 8 fused B-frags for this block's 128 x
    const int xbase = blockIdx.x * XPB;
    S8 hc;
    hc.u[0] = (c32 < 16) ? (unsigned short)0 : (unsigned short)0x3F80;
    hc.u[1] = hc.u[0];
    hc.u[2]=0; hc.u[3]=0; hc.u[4]=0; hc.u[5]=0; hc.u[6]=0; hc.u[7]=0;
    const int xcol0 = xbase + (c32 & 15);
    const short8* Bsel = (c32 < 16) ? BR : BV;
    short8 bf[8];
#pragma unroll
    for (int j = 0; j < 8; ++j)
        bf[j] = (half == 0) ? Bsel[xcol0 + j*16] : hc.v;

    float mn[8];
#pragma unroll
    for (int j = 0; j < 8; ++j) mn[j] = INFINITY;

    const f16v Z = (f16v)(0.0f);
    const int abase0 = (blockIdx.y * 2 + wave) * 512 + c32;

#pragma unroll 2
    for (int t = 0; t < 16; ++t) {         // 16 y-tiles of 32
        const short8 a = Abase[abase0 + t*32];
#pragma unroll
        for (int j = 0; j < 8; ++j) {
            const f16v d = __builtin_amdgcn_mfma_f32_32x32x16_bf16(a, bf[j], Z, 0, 0, 0);
            fold16(d, mn[j]);
        }
    }

    // other 16 rows live in the xor-32 partner lane (same column)
#pragma unroll
    for (int j = 0; j < 8; ++j)
        mn[j] = fminf(mn[j], __shfl_xor(mn[j], 32));

    if (half == 0) {
        unsigned* mins = (unsigned*)ws + WS_MINS;
        const int var = (c32 < 16) ? 0 : 1;
        const int e0 = ((slot*2 + var) << 13) + xcol0;
#pragma unroll
        for (int j = 0; j < 8; ++j)
            atomicMin(&mins[e0 + j*16], fenc(mn[j]));
    }
}

// 128 blocks x 256: one thread per (slot,x). Decode, add |x|^2, sum, ticket-out.
__global__ void __launch_bounds__(256)
finalize_kernel(float* __restrict__ ws, float* __restrict__ out) {
    const int g = blockIdx.x * 256 + threadIdx.x;   // 0..32767
    const int slot = g >> 13;
    const int x    = g & (N-1);
    const int dir  = slot & 1;
    const int b    = slot >> 1;
    const int gX   = dir*2 + b;
    const unsigned* mins = (const unsigned*)ws + WS_MINS;
    float s = fdec(mins[((slot*2 + 0) << 13) + x]) + ws[OFF_XXR(gX) + x]
            + fdec(mins[((slot*2 + 1) << 13) + x]) + ws[OFF_XXV(gX) + x];
    for (int off = 32; off; off >>= 1)
        s += __shfl_down(s, off);
    __shared__ float sm[4];
    const int wave = threadIdx.x >> 6, lane = threadIdx.x & 63;
    if (lane == 0) sm[wave] = s;
    __syncthreads();
    if (threadIdx.x == 0) {
        const float bs = sm[0] + sm[1] + sm[2] + sm[3];
        atomicAdd(ws + WS_ACC, bs);
        __threadfence();
        const unsigned t = atomicAdd(&((unsigned*)ws)[WS_TICKET], 1u);
        if (t == gridDim.x - 1) {
            __threadfence();
            const float total = atomicAdd(ws + WS_ACC, 0.0f);  // atomic read
            out[0] = total * (1.0f / 16384.0f);
        }
    }
}

extern "C" void kernel_launch(void* const* d_in, const int* in_sizes, int n_in,
                              void* d_out, int out_size, void* d_ws, size_t ws_size,
                              hipStream_t stream) {
    const float* preds = (const float*)d_in[0];
    const float* gts   = (const float*)d_in[1];
    float* ws  = (float*)d_ws;
    float* out = (float*)d_out;

    gmin_kernel<<<dim3(64), dim3(256), 0, stream>>>(preds, gts, ws);
    pack_kernel<<<dim3(128), dim3(256), 0, stream>>>(preds, gts, ws);
    chamfer_kernel<<<dim3(N/XPB, 8, 4), dim3(CBLK), 0, stream>>>(ws);
    finalize_kernel<<<dim3(128), dim3(256), 0, stream>>>(ws, out);
}